// Round 7
// baseline (155.093 us; speedup 1.0000x reference)
//
#include <hip/hip_runtime.h>
#include <math.h>

#define M_ 3
#define B_ 64
#define D_ 512
#define H4 128     // D/4
#define HIST_ 5
#define BD (B_ * D_)        // 32768
#define INVSCALE 0.04419417382415922f   // 1/sqrt(512)
#define LOG2E 1.4426950408889634f

__device__ __forceinline__ float wave_sum64(float v) {
#pragma unroll
    for (int o = 32; o >= 1; o >>= 1) v += __shfl_xor(v, o, 64);
    return v;
}

__device__ __forceinline__ float sigmoidf(float x) {
    return 1.0f / (1.0f + __expf(-x));
}

// ---------------------------------------------------------------------------
// k_proj: partial GEMM ypart[m,b,kq,d] = sum_{k in kq} x[m,b,k]*W[m,d,k].
// grid = 768 blocks (3/CU), 256 threads. Blocks 0..127 also zero out[0..BD)
// (stream order => lands before any atomics). Block 0 writes attention
// weights (pure function of gamma).
// ---------------------------------------------------------------------------
__global__ __launch_bounds__(256) void k_proj(
    const float* __restrict__ x, const float* __restrict__ pW,
    const float* __restrict__ gamma, float* __restrict__ ypart,
    float* __restrict__ out)
{
    const int m    = blockIdx.x >> 8;
    const int r    = blockIdx.x & 255;
    const int kq   = r >> 6;
    const int rem2 = r & 63;
    const int dh   = rem2 >> 5;
    const int bp   = rem2 & 31;
    const int b0   = bp << 1;
    const int t    = threadIdx.x;
    const int d    = (dh << 8) + t;

    if (blockIdx.x < 128)
        out[(blockIdx.x << 8) + t] = 0.f;

    __shared__ __align__(16) float4 xs[2][32];
    if (t < 64) {
        const int rr = t >> 5, cc = t & 31;
        xs[rr][cc] = ((const float4*)(x + (size_t)(m * B_ + b0 + rr) * D_ + kq * 128))[cc];
    }
    __syncthreads();

    const float4* wr = (const float4*)(pW + (size_t)m * D_ * D_ + (size_t)d * D_ + kq * 128);
    float acc0 = 0.f, acc1 = 0.f;
#pragma unroll
    for (int k = 0; k < 32; ++k) {
        const float4 w = wr[k];
        const float4 a = xs[0][k];
        const float4 b = xs[1][k];
        acc0 = fmaf(w.x, a.x, acc0); acc0 = fmaf(w.y, a.y, acc0);
        acc0 = fmaf(w.z, a.z, acc0); acc0 = fmaf(w.w, a.w, acc0);
        acc1 = fmaf(w.x, b.x, acc1); acc1 = fmaf(w.y, b.y, acc1);
        acc1 = fmaf(w.z, b.z, acc1); acc1 = fmaf(w.w, b.w, acc1);
    }
    const size_t idx0 = (size_t)(m * B_ + b0) * 2048 + kq * 512 + d;
    ypart[idx0]        = acc0;
    ypart[idx0 + 2048] = acc1;

    if (blockIdx.x == 0 && t == 0) {
        const float g01 = sigmoidf(gamma[1]), g02 = sigmoidf(gamma[2]);
        const float g10 = sigmoidf(gamma[3]), g12 = sigmoidf(gamma[5]);
        const float g20 = sigmoidf(gamma[6]), g21 = sigmoidf(gamma[7]);
        const float s0 = 0.5f * (g01 + g02);
        const float s1 = 0.5f * (g10 + g12);
        const float s2 = 0.5f * (g20 + g21);
        const float mx = fmaxf(s0, fmaxf(s1, s2));
        const float e0 = __expf(s0 - mx), e1 = __expf(s1 - mx), e2 = __expf(s2 - mx);
        const float den = e0 + e1 + e2;
        out[BD + 0] = e0 / den;
        out[BD + 1] = e1 / den;
        out[BD + 2] = e2 / den;
    }
}

// ---------------------------------------------------------------------------
// k_lnmlp: per (m,b) row — sum 4 ypart quarters + pb, LayerNorm+ReLU,
// MLP1 (4-way K-split), MLP2, wf = p*sigmoid, Ssum. Adds wf/3 into out.
// grid = 192 blocks, 512 threads (thread = d).
// ---------------------------------------------------------------------------
__global__ __launch_bounds__(512) void k_lnmlp(
    const float* __restrict__ ypart, const float* __restrict__ pb,
    const float* __restrict__ lg, const float* __restrict__ lb,
    const float* __restrict__ W1, const float* __restrict__ b1,
    const float* __restrict__ W2, const float* __restrict__ b2,
    float* __restrict__ wf, float* __restrict__ Ssum,
    float* __restrict__ out)
{
    const int m = blockIdx.x >> 6;
    const int b = blockIdx.x & 63;
    const int t = threadIdx.x;
    __shared__ __align__(16) float ps[D_];
    __shared__ __align__(16) float hs[H4];
    __shared__ __align__(16) float hpart[512];
    __shared__ float red[8];

    const size_t rbase = (size_t)(m * B_ + b) * 2048;
    const float y = ypart[rbase + t] + ypart[rbase + 512 + t]
                  + ypart[rbase + 1024 + t] + ypart[rbase + 1536 + t]
                  + pb[m * D_ + t];

    float s = wave_sum64(y);
    if ((t & 63) == 0) red[t >> 6] = s;
    __syncthreads();
    const float mean = (red[0]+red[1]+red[2]+red[3]+red[4]+red[5]+red[6]+red[7]) * (1.f / D_);
    __syncthreads();
    const float v = y - mean;
    float vs = wave_sum64(v * v);
    if ((t & 63) == 0) red[t >> 6] = vs;
    __syncthreads();
    const float inv = rsqrtf((red[0]+red[1]+red[2]+red[3]+red[4]+red[5]+red[6]+red[7]) * (1.f / D_) + 1e-5f);
    const float p = fmaxf(fmaf(v * inv, lg[m * D_ + t], lb[m * D_ + t]), 0.f);
    ps[t] = p;
    __syncthreads();

    // MLP1: thread -> (r = t&127, seg = t>>7)
    {
        const int r = t & 127, seg = t >> 7;
        const float4* w1 = (const float4*)(W1 + ((size_t)m * H4 + r) * D_) + (seg << 5);
        const float4* pv = (const float4*)ps + (seg << 5);
        float a1 = 0.f;
#pragma unroll
        for (int k = 0; k < 32; ++k) {
            const float4 w = w1[k], pp = pv[k];
            a1 = fmaf(w.x, pp.x, a1); a1 = fmaf(w.y, pp.y, a1);
            a1 = fmaf(w.z, pp.z, a1); a1 = fmaf(w.w, pp.w, a1);
        }
        hpart[t] = a1;
    }
    __syncthreads();
    if (t < H4)
        hs[t] = fmaxf(hpart[t] + hpart[t + 128] + hpart[t + 256] + hpart[t + 384]
                      + b1[m * H4 + t], 0.f);
    __syncthreads();

    // MLP2
    const float4* w2 = (const float4*)(W2 + ((size_t)m * D_ + t) * H4);
    const float4* hv = (const float4*)hs;
    float a2 = 0.f;
#pragma unroll
    for (int k = 0; k < H4 / 4; ++k) {
        const float4 w = w2[k], hh = hv[k];
        a2 = fmaf(w.x, hh.x, a2); a2 = fmaf(w.y, hh.y, a2);
        a2 = fmaf(w.z, hh.z, a2); a2 = fmaf(w.w, hh.w, a2);
    }
    const float cw = sigmoidf(a2 + b2[m * D_ + t]);
    const float wv = p * cw;
    wf[(size_t)(m * B_ + b) * D_ + t] = wv;
    atomicAdd(&out[b * D_ + t], wv * (1.f / 3.f));

    float tot = wave_sum64(wv);
    if ((t & 63) == 0) red[t >> 6] = tot;
    __syncthreads();
    if (t == 0)
        Ssum[m * B_ + b] = red[0]+red[1]+red[2]+red[3]+red[4]+red[5]+red[6]+red[7];
}

// ---------------------------------------------------------------------------
// k_fuseAH: persistent-block fusion of pass A (units 0..3071) and history
// (units 3072..3839). grid = 1280 blocks x 3 units each (5 blocks/CU, all
// co-resident, no tail). Layouts identical to R6 (R4-proven).
// wf >= 0 (relu*sigmoid) => clip(t,-c,c) = min(t,c); passA inner loop uses
// pre-scaled a08/a02: f*log2e = min(a08*u, c08) + a02*u  (3 VALU + exp + 2).
// ---------------------------------------------------------------------------
__global__ __launch_bounds__(256) void k_fuseAH(
    const float* __restrict__ wf, const float* __restrict__ constraint,
    const float* __restrict__ gamma, const float* __restrict__ mbias,
    const float* __restrict__ Ssum, float* __restrict__ HT,
    float* __restrict__ out)
{
    const int t = threadIdx.x;
    __shared__ __align__(8) float2 part[256];

    for (int u = blockIdx.x; u < 3840; u += 1280) {
        if (u < 3072) {
            // ---- pass A unit ----
            const int i    = u >> 10;
            const int rem  = u & 1023;
            const int b    = rem >> 4;
            const int dc   = rem & 15;
            const int d    = (dc << 5) + (t & 31);
            const int esec = t >> 5;               // 0..7, 64 e's each
            const int jA   = (i == 0) ? 1 : 0;

            const float c08 = constraint[i] * (0.8f * LOG2E);
            const float a   = wf[(size_t)i * BD + b * D_ + d];
            const float a08 = a * (0.8f * INVSCALE * LOG2E);
            const float a02 = a * (0.2f * INVSCALE * LOG2E);
            const float* uAp = wf + (size_t)jA * BD + b * D_ + (esec << 6);

            float sA = 0.f, dA = 0.f;
#pragma unroll 4
            for (int e = 0; e < 64; e += 4) {
                const float4 u4 = *(const float4*)(uAp + e);
                const float uu[4] = {u4.x, u4.y, u4.z, u4.w};
#pragma unroll
                for (int k = 0; k < 4; ++k) {
                    const float v1 = a08 * uu[k];
                    const float v2 = fminf(v1, c08);
                    const float f  = fmaf(a02, uu[k], v2);
                    const float p  = __builtin_amdgcn_exp2f(f);
                    sA += p;
                    dA = fmaf(p, uu[k], dA);
                }
            }

            part[t] = make_float2(sA, dA);
            __syncthreads();
            if (t < 32) {
                float Ss = 0.f, Sd = 0.f;
#pragma unroll
                for (int k = 0; k < 8; ++k) {
                    const float2 pp = part[t + (k << 5)];
                    Ss += pp.x; Sd += pp.y;
                }
                const float gA = sigmoidf(gamma[i * 3 + jA]);
                const float pv = gA * (Sd / Ss + mbias[i * 3 + jA] * Ssum[jA * B_ + b]);
                atomicAdd(&out[b * D_ + d], pv * (1.f / 6.f));
            }
            __syncthreads();   // part[] reused by next unit
        } else {
            // ---- history unit (R4 layout: HT[i][e][d], thread = d) ----
            const int hb = u - 3072;
            const int i  = hb >> 8;
            const int e0 = (hb & 255) << 1;
            const int j  = (i == 0) ? 1 : 0;
            const float c = constraint[i];
            const float* wfi = wf + (size_t)i * BD;
            const float* wfj = wf + (size_t)j * BD;

            float h00 = 0.f, h01 = 0.f, h10 = 0.f, h11 = 0.f;
#pragma unroll 4
            for (int b = 0; b < B_; ++b) {
                const float a0 = wfi[b * D_ + t]       * INVSCALE;
                const float a1 = wfi[b * D_ + t + 256] * INVSCALE;
                const float2 u2 = *(const float2*)(wfj + b * D_ + e0);
                float tt, mm;
                tt = a0 * u2.x; mm = fminf(tt, c); h00 = fmaf(0.8f, mm, fmaf(0.2f, tt, h00));
                tt = a1 * u2.x; mm = fminf(tt, c); h01 = fmaf(0.8f, mm, fmaf(0.2f, tt, h01));
                tt = a0 * u2.y; mm = fminf(tt, c); h10 = fmaf(0.8f, mm, fmaf(0.2f, tt, h10));
                tt = a1 * u2.y; mm = fminf(tt, c); h11 = fmaf(0.8f, mm, fmaf(0.2f, tt, h11));
            }
            const float hsc = LOG2E / (float)(B_ * HIST_);
            float* r0 = HT + ((size_t)(i << 9) + e0) * D_;
            r0[t]             = h00 * hsc;
            r0[t + 256]       = h01 * hsc;
            r0[D_ + t]        = h10 * hsc;
            r0[D_ + t + 256]  = h11 * hsc;
        }
    }
}

// ---------------------------------------------------------------------------
// k_passB: second-j softmax-dot with hist = HT (transposed; scalar hp[k*D_]
// reads coalesced across consecutive-d lanes — R4/R6 proven pattern).
// Persistent blocks: grid = 1024 x 3 units (4/CU, all resident, no tail).
// ---------------------------------------------------------------------------
__global__ __launch_bounds__(256) void k_passB(
    const float* __restrict__ wf, const float* __restrict__ constraint,
    const float* __restrict__ gamma, const float* __restrict__ mbias,
    const float* __restrict__ HT, const float* __restrict__ Ssum,
    float* __restrict__ out)
{
    const int t = threadIdx.x;
    __shared__ __align__(8) float2 part[256];

    for (int u = blockIdx.x; u < 3072; u += 1024) {
        const int i    = u >> 10;
        const int rem  = u & 1023;
        const int b    = rem >> 4;
        const int dc   = rem & 15;
        const int d    = (dc << 5) + (t & 31);
        const int esec = t >> 5;               // 0..7, 64 e's each
        const int jB   = (i == 2) ? 1 : 2;

        const float cl = constraint[i] * LOG2E;
        const float a  = wf[(size_t)i * BD + b * D_ + d] * (INVSCALE * LOG2E);
        const float* uBp = wf + (size_t)jB * BD + b * D_ + (esec << 6);
        const float* hp  = HT + ((size_t)(i << 9) + (esec << 6)) * D_ + d;

        float sB = 0.f, dB = 0.f;
#pragma unroll 4
        for (int e = 0; e < 64; e += 4) {
            const float4 u4 = *(const float4*)(uBp + e);
            const float uu[4] = {u4.x, u4.y, u4.z, u4.w};
            float hh[4];
#pragma unroll
            for (int k = 0; k < 4; ++k) hh[k] = hp[(size_t)k * D_];
            hp += 4 * D_;
#pragma unroll
            for (int k = 0; k < 4; ++k) {
                const float tt = a * uu[k];
                const float df = tt - hh[k];
                const float mm = fminf(fmaxf(df, -cl), cl);
                const float f  = fmaf(0.8f, hh[k] + mm, 0.2f * tt);
                const float p  = __builtin_amdgcn_exp2f(f);
                sB += p;
                dB = fmaf(p, uu[k], dB);
            }
        }

        part[t] = make_float2(sB, dB);
        __syncthreads();
        if (t < 32) {
            float Ss = 0.f, Sd = 0.f;
#pragma unroll
            for (int k = 0; k < 8; ++k) {
                const float2 pp = part[t + (k << 5)];
                Ss += pp.x; Sd += pp.y;
            }
            const float gB = sigmoidf(gamma[i * 3 + jB]);
            const float pv = gB * (Sd / Ss + mbias[i * 3 + jB] * Ssum[jB * B_ + b]);
            atomicAdd(&out[b * D_ + d], pv * (1.f / 6.f));
        }
        __syncthreads();   // part[] reused by next unit
    }
}

// ---------------------------------------------------------------------------
extern "C" void kernel_launch(void* const* d_in, const int* in_sizes, int n_in,
                              void* d_out, int out_size, void* d_ws, size_t ws_size,
                              hipStream_t stream) {
    const float* x    = (const float*)d_in[0];
    const float* pW   = (const float*)d_in[1];
    const float* pb   = (const float*)d_in[2];
    const float* lg   = (const float*)d_in[3];
    const float* lb   = (const float*)d_in[4];
    const float* W1   = (const float*)d_in[5];
    const float* b1   = (const float*)d_in[6];
    const float* W2   = (const float*)d_in[7];
    const float* b2   = (const float*)d_in[8];
    const float* gamma= (const float*)d_in[9];
    const float* mb   = (const float*)d_in[10];
    const float* cons = (const float*)d_in[11];
    float* out = (float*)d_out;

    float* ws    = (float*)d_ws;
    float* wf    = ws;                 // 98304 floats
    float* Ssum  = ws + 98304;         // 192
    float* HT    = ws + 98496;         // 786432 (HT[i][e][d], *LOG2E)
    float* ypart = ws + 884928;        // 393216   (total ~4.9 MB)

    k_proj  <<<dim3(768),     dim3(256), 0, stream>>>(x, pW, gamma, ypart, out);
    k_lnmlp <<<dim3(M_ * B_), dim3(512), 0, stream>>>(ypart, pb, lg, lb, W1, b1, W2, b2, wf, Ssum, out);
    k_fuseAH<<<dim3(1280),    dim3(256), 0, stream>>>(wf, cons, gamma, mb, Ssum, HT, out);
    k_passB <<<dim3(1024),    dim3(256), 0, stream>>>(wf, cons, gamma, mb, HT, Ssum, out);
}

// Round 8
// 148.499 us; speedup vs baseline: 1.0444x; 1.0444x over previous
//
#include <hip/hip_runtime.h>
#include <math.h>

#define M_ 3
#define B_ 64
#define D_ 512
#define H4 128     // D/4
#define HIST_ 5
#define BD (B_ * D_)        // 32768
#define INVSCALE 0.04419417382415922f   // 1/sqrt(512)
#define LOG2E 1.4426950408889634f

__device__ __forceinline__ float wave_sum64(float v) {
#pragma unroll
    for (int o = 32; o >= 1; o >>= 1) v += __shfl_xor(v, o, 64);
    return v;
}

__device__ __forceinline__ float sigmoidf(float x) {
    return 1.0f / (1.0f + __expf(-x));
}

// ---------------------------------------------------------------------------
// k_proj: partial GEMM ypart[m,b,kq,d] = sum_{k in kq} x[m,b,k]*W[m,d,k].
// grid = 768 blocks (3/CU), 256 threads. Blocks 0..127 also zero out[0..BD)
// (stream order => lands before any atomics). Block 0 writes attention
// weights (pure function of gamma).
// ---------------------------------------------------------------------------
__global__ __launch_bounds__(256) void k_proj(
    const float* __restrict__ x, const float* __restrict__ pW,
    const float* __restrict__ gamma, float* __restrict__ ypart,
    float* __restrict__ out)
{
    const int m    = blockIdx.x >> 8;
    const int r    = blockIdx.x & 255;
    const int kq   = r >> 6;
    const int rem2 = r & 63;
    const int dh   = rem2 >> 5;
    const int bp   = rem2 & 31;
    const int b0   = bp << 1;
    const int t    = threadIdx.x;
    const int d    = (dh << 8) + t;

    if (blockIdx.x < 128)
        out[(blockIdx.x << 8) + t] = 0.f;

    __shared__ __align__(16) float4 xs[2][32];
    if (t < 64) {
        const int rr = t >> 5, cc = t & 31;
        xs[rr][cc] = ((const float4*)(x + (size_t)(m * B_ + b0 + rr) * D_ + kq * 128))[cc];
    }
    __syncthreads();

    const float4* wr = (const float4*)(pW + (size_t)m * D_ * D_ + (size_t)d * D_ + kq * 128);
    float acc0 = 0.f, acc1 = 0.f;
#pragma unroll
    for (int k = 0; k < 32; ++k) {
        const float4 w = wr[k];
        const float4 a = xs[0][k];
        const float4 b = xs[1][k];
        acc0 = fmaf(w.x, a.x, acc0); acc0 = fmaf(w.y, a.y, acc0);
        acc0 = fmaf(w.z, a.z, acc0); acc0 = fmaf(w.w, a.w, acc0);
        acc1 = fmaf(w.x, b.x, acc1); acc1 = fmaf(w.y, b.y, acc1);
        acc1 = fmaf(w.z, b.z, acc1); acc1 = fmaf(w.w, b.w, acc1);
    }
    const size_t idx0 = (size_t)(m * B_ + b0) * 2048 + kq * 512 + d;
    ypart[idx0]        = acc0;
    ypart[idx0 + 2048] = acc1;

    if (blockIdx.x == 0 && t == 0) {
        const float g01 = sigmoidf(gamma[1]), g02 = sigmoidf(gamma[2]);
        const float g10 = sigmoidf(gamma[3]), g12 = sigmoidf(gamma[5]);
        const float g20 = sigmoidf(gamma[6]), g21 = sigmoidf(gamma[7]);
        const float s0 = 0.5f * (g01 + g02);
        const float s1 = 0.5f * (g10 + g12);
        const float s2 = 0.5f * (g20 + g21);
        const float mx = fmaxf(s0, fmaxf(s1, s2));
        const float e0 = __expf(s0 - mx), e1 = __expf(s1 - mx), e2 = __expf(s2 - mx);
        const float den = e0 + e1 + e2;
        out[BD + 0] = e0 / den;
        out[BD + 1] = e1 / den;
        out[BD + 2] = e2 / den;
    }
}

// ---------------------------------------------------------------------------
// k_lnmlp: per (m,b) row — sum 4 ypart quarters + pb, LayerNorm+ReLU,
// MLP1 (4-way K-split), MLP2, wf = p*sigmoid, Ssum. Adds wf/3 into out.
// grid = 192 blocks, 512 threads (thread = d).
// ---------------------------------------------------------------------------
__global__ __launch_bounds__(512) void k_lnmlp(
    const float* __restrict__ ypart, const float* __restrict__ pb,
    const float* __restrict__ lg, const float* __restrict__ lb,
    const float* __restrict__ W1, const float* __restrict__ b1,
    const float* __restrict__ W2, const float* __restrict__ b2,
    float* __restrict__ wf, float* __restrict__ Ssum,
    float* __restrict__ out)
{
    const int m = blockIdx.x >> 6;
    const int b = blockIdx.x & 63;
    const int t = threadIdx.x;
    __shared__ __align__(16) float ps[D_];
    __shared__ __align__(16) float hs[H4];
    __shared__ __align__(16) float hpart[512];
    __shared__ float red[8];

    const size_t rbase = (size_t)(m * B_ + b) * 2048;
    const float y = ypart[rbase + t] + ypart[rbase + 512 + t]
                  + ypart[rbase + 1024 + t] + ypart[rbase + 1536 + t]
                  + pb[m * D_ + t];

    float s = wave_sum64(y);
    if ((t & 63) == 0) red[t >> 6] = s;
    __syncthreads();
    const float mean = (red[0]+red[1]+red[2]+red[3]+red[4]+red[5]+red[6]+red[7]) * (1.f / D_);
    __syncthreads();
    const float v = y - mean;
    float vs = wave_sum64(v * v);
    if ((t & 63) == 0) red[t >> 6] = vs;
    __syncthreads();
    const float inv = rsqrtf((red[0]+red[1]+red[2]+red[3]+red[4]+red[5]+red[6]+red[7]) * (1.f / D_) + 1e-5f);
    const float p = fmaxf(fmaf(v * inv, lg[m * D_ + t], lb[m * D_ + t]), 0.f);
    ps[t] = p;
    __syncthreads();

    // MLP1: thread -> (r = t&127, seg = t>>7)
    {
        const int r = t & 127, seg = t >> 7;
        const float4* w1 = (const float4*)(W1 + ((size_t)m * H4 + r) * D_) + (seg << 5);
        const float4* pv = (const float4*)ps + (seg << 5);
        float a1 = 0.f;
#pragma unroll
        for (int k = 0; k < 32; ++k) {
            const float4 w = w1[k], pp = pv[k];
            a1 = fmaf(w.x, pp.x, a1); a1 = fmaf(w.y, pp.y, a1);
            a1 = fmaf(w.z, pp.z, a1); a1 = fmaf(w.w, pp.w, a1);
        }
        hpart[t] = a1;
    }
    __syncthreads();
    if (t < H4)
        hs[t] = fmaxf(hpart[t] + hpart[t + 128] + hpart[t + 256] + hpart[t + 384]
                      + b1[m * H4 + t], 0.f);
    __syncthreads();

    // MLP2
    const float4* w2 = (const float4*)(W2 + ((size_t)m * D_ + t) * H4);
    const float4* hv = (const float4*)hs;
    float a2 = 0.f;
#pragma unroll
    for (int k = 0; k < H4 / 4; ++k) {
        const float4 w = w2[k], hh = hv[k];
        a2 = fmaf(w.x, hh.x, a2); a2 = fmaf(w.y, hh.y, a2);
        a2 = fmaf(w.z, hh.z, a2); a2 = fmaf(w.w, hh.w, a2);
    }
    const float cw = sigmoidf(a2 + b2[m * D_ + t]);
    const float wv = p * cw;
    wf[(size_t)(m * B_ + b) * D_ + t] = wv;
    atomicAdd(&out[b * D_ + t], wv * (1.f / 3.f));

    float tot = wave_sum64(wv);
    if ((t & 63) == 0) red[t >> 6] = tot;
    __syncthreads();
    if (t == 0)
        Ssum[m * B_ + b] = red[0]+red[1]+red[2]+red[3]+red[4]+red[5]+red[6]+red[7];
}

// ---------------------------------------------------------------------------
// k_fuseAH: R6 grid-partitioned fusion (plain grid, no persistent loop).
//  Blocks [0,3072): pass A (hist=0). block=(i,b,32-d chunk), 256 thr =
//    32 d x 8 e-sections (64 e each); LDS reduce; atomicAdd into out.
//    wf >= 0 => clip(t,-c,c) = min(t,c); pre-scaled a08/a02 form:
//    f*log2e = min(a08*u, c08) + a02*u   (3 VALU + exp + 2 per e).
//  Blocks [3072,3840): history, TRANSPOSED HT[i][e][d] pre-scaled by LOG2E.
//    block=(i, e-pair), thread = d & d+256; uniform wfj float2, coalesced wfi.
// ---------------------------------------------------------------------------
__global__ __launch_bounds__(256) void k_fuseAH(
    const float* __restrict__ wf, const float* __restrict__ constraint,
    const float* __restrict__ gamma, const float* __restrict__ mbias,
    const float* __restrict__ Ssum, float* __restrict__ HT,
    float* __restrict__ out)
{
    const int t = threadIdx.x;

    if (blockIdx.x < 3072) {
        // ---- pass A ----
        const int i    = blockIdx.x >> 10;
        const int rem  = blockIdx.x & 1023;
        const int b    = rem >> 4;
        const int dc   = rem & 15;
        const int d    = (dc << 5) + (t & 31);
        const int esec = t >> 5;               // 0..7, 64 e's each
        const int jA   = (i == 0) ? 1 : 0;

        const float c08 = constraint[i] * (0.8f * LOG2E);
        const float a   = wf[(size_t)i * BD + b * D_ + d];
        const float a08 = a * (0.8f * INVSCALE * LOG2E);
        const float a02 = a * (0.2f * INVSCALE * LOG2E);
        const float* uAp = wf + (size_t)jA * BD + b * D_ + (esec << 6);

        float sA = 0.f, dA = 0.f;
#pragma unroll 4
        for (int e = 0; e < 64; e += 4) {
            const float4 u4 = *(const float4*)(uAp + e);
            const float uu[4] = {u4.x, u4.y, u4.z, u4.w};
#pragma unroll
            for (int k = 0; k < 4; ++k) {
                const float v1 = a08 * uu[k];
                const float v2 = fminf(v1, c08);
                const float f  = fmaf(a02, uu[k], v2);
                const float p  = __builtin_amdgcn_exp2f(f);
                sA += p;
                dA = fmaf(p, uu[k], dA);
            }
        }

        __shared__ __align__(8) float2 part[256];
        part[t] = make_float2(sA, dA);
        __syncthreads();
        if (t < 32) {
            float Ss = 0.f, Sd = 0.f;
#pragma unroll
            for (int k = 0; k < 8; ++k) {
                const float2 pp = part[t + (k << 5)];
                Ss += pp.x; Sd += pp.y;
            }
            const float gA = sigmoidf(gamma[i * 3 + jA]);
            const float pv = gA * (Sd / Ss + mbias[i * 3 + jA] * Ssum[jA * B_ + b]);
            atomicAdd(&out[b * D_ + d], pv * (1.f / 6.f));
        }
        return;
    }

    // ---- history (R4 layout: HT[i][e][d], thread = d); min() since t >= 0 ----
    const int hb = blockIdx.x - 3072;
    const int i  = hb >> 8;
    const int e0 = (hb & 255) << 1;
    const int j  = (i == 0) ? 1 : 0;
    const float c = constraint[i];
    const float* wfi = wf + (size_t)i * BD;
    const float* wfj = wf + (size_t)j * BD;

    float h00 = 0.f, h01 = 0.f, h10 = 0.f, h11 = 0.f;
#pragma unroll 4
    for (int b = 0; b < B_; ++b) {
        const float a0 = wfi[b * D_ + t]       * INVSCALE;
        const float a1 = wfi[b * D_ + t + 256] * INVSCALE;
        const float2 u2 = *(const float2*)(wfj + b * D_ + e0);
        float tt, mm;
        tt = a0 * u2.x; mm = fminf(tt, c); h00 = fmaf(0.8f, mm, fmaf(0.2f, tt, h00));
        tt = a1 * u2.x; mm = fminf(tt, c); h01 = fmaf(0.8f, mm, fmaf(0.2f, tt, h01));
        tt = a0 * u2.y; mm = fminf(tt, c); h10 = fmaf(0.8f, mm, fmaf(0.2f, tt, h10));
        tt = a1 * u2.y; mm = fminf(tt, c); h11 = fmaf(0.8f, mm, fmaf(0.2f, tt, h11));
    }
    const float hsc = LOG2E / (float)(B_ * HIST_);
    float* r0 = HT + ((size_t)(i << 9) + e0) * D_;
    r0[t]             = h00 * hsc;
    r0[t + 256]       = h01 * hsc;
    r0[D_ + t]        = h10 * hsc;
    r0[D_ + t + 256]  = h11 * hsc;
}

// ---------------------------------------------------------------------------
// k_passB: second-j softmax-dot with hist = HT (transposed; scalar hp[k*D_]
// reads coalesced across the 32 consecutive-d lanes — R4/R6 proven pattern).
// block=(i,b,32-d chunk), 256 thr = 32 d x 8 e-sections (64 e each).
// atomicAdd gB*(dotB/sumB + mbB*S_jB)/6 into out. grid = 3072 blocks.
// ---------------------------------------------------------------------------
__global__ __launch_bounds__(256) void k_passB(
    const float* __restrict__ wf, const float* __restrict__ constraint,
    const float* __restrict__ gamma, const float* __restrict__ mbias,
    const float* __restrict__ HT, const float* __restrict__ Ssum,
    float* __restrict__ out)
{
    const int i    = blockIdx.x >> 10;
    const int rem  = blockIdx.x & 1023;
    const int b    = rem >> 4;
    const int dc   = rem & 15;
    const int t    = threadIdx.x;
    const int d    = (dc << 5) + (t & 31);
    const int esec = t >> 5;               // 0..7, 64 e's each
    const int jB   = (i == 2) ? 1 : 2;

    const float cl = constraint[i] * LOG2E;
    const float a  = wf[(size_t)i * BD + b * D_ + d] * (INVSCALE * LOG2E);
    const float* uBp = wf + (size_t)jB * BD + b * D_ + (esec << 6);
    const float* Hp  = HT + ((size_t)(i << 9) + (esec << 6)) * D_ + d;

    float sB = 0.f, dB = 0.f;
    const float* hp = Hp;
#pragma unroll 4
    for (int e = 0; e < 64; e += 4) {
        const float4 u4 = *(const float4*)(uBp + e);
        const float uu[4] = {u4.x, u4.y, u4.z, u4.w};
        float hh[4];
#pragma unroll
        for (int k = 0; k < 4; ++k) hh[k] = hp[(size_t)k * D_];
        hp += 4 * D_;
#pragma unroll
        for (int k = 0; k < 4; ++k) {
            const float tt = a * uu[k];
            const float df = tt - hh[k];
            const float mm = fminf(fmaxf(df, -cl), cl);
            const float f  = fmaf(0.8f, hh[k] + mm, 0.2f * tt);
            const float p  = __builtin_amdgcn_exp2f(f);
            sB += p;
            dB = fmaf(p, uu[k], dB);
        }
    }

    __shared__ __align__(8) float2 part[256];
    part[t] = make_float2(sB, dB);
    __syncthreads();
    if (t < 32) {
        float Ss = 0.f, Sd = 0.f;
#pragma unroll
        for (int k = 0; k < 8; ++k) {
            const float2 pp = part[t + (k << 5)];
            Ss += pp.x; Sd += pp.y;
        }
        const float gB = sigmoidf(gamma[i * 3 + jB]);
        const float pv = gB * (Sd / Ss + mbias[i * 3 + jB] * Ssum[jB * B_ + b]);
        atomicAdd(&out[b * D_ + d], pv * (1.f / 6.f));
    }
}

// ---------------------------------------------------------------------------
extern "C" void kernel_launch(void* const* d_in, const int* in_sizes, int n_in,
                              void* d_out, int out_size, void* d_ws, size_t ws_size,
                              hipStream_t stream) {
    const float* x    = (const float*)d_in[0];
    const float* pW   = (const float*)d_in[1];
    const float* pb   = (const float*)d_in[2];
    const float* lg   = (const float*)d_in[3];
    const float* lb   = (const float*)d_in[4];
    const float* W1   = (const float*)d_in[5];
    const float* b1   = (const float*)d_in[6];
    const float* W2   = (const float*)d_in[7];
    const float* b2   = (const float*)d_in[8];
    const float* gamma= (const float*)d_in[9];
    const float* mb   = (const float*)d_in[10];
    const float* cons = (const float*)d_in[11];
    float* out = (float*)d_out;

    float* ws    = (float*)d_ws;
    float* wf    = ws;                 // 98304 floats
    float* Ssum  = ws + 98304;         // 192
    float* HT    = ws + 98496;         // 786432 (HT[i][e][d], *LOG2E)
    float* ypart = ws + 884928;        // 393216   (total ~4.9 MB)

    k_proj  <<<dim3(768),      dim3(256), 0, stream>>>(x, pW, gamma, ypart, out);
    k_lnmlp <<<dim3(M_ * B_),  dim3(512), 0, stream>>>(ypart, pb, lg, lb, W1, b1, W2, b2, wf, Ssum, out);
    k_fuseAH<<<dim3(3840),     dim3(256), 0, stream>>>(wf, cons, gamma, mb, Ssum, HT, out);
    k_passB <<<dim3(M_ * 1024),dim3(256), 0, stream>>>(wf, cons, gamma, mb, HT, Ssum, out);
}